// Round 5
// baseline (877.817 us; speedup 1.0000x reference)
//
#include <hip/hip_runtime.h>

#define N_NODES 40000
#define N_EDGES 320000
#define EPSBN 1e-5f

typedef float floatx4 __attribute__((ext_vector_type(4)));

// ---- setup: w1t[col*32 + j] = W1[j*1024 + col]  (f32 transpose so j runs contiguously)
__global__ void k_setup(const float* __restrict__ W1, float* __restrict__ w1t) {
  int i = blockIdx.x * 256 + threadIdx.x;   // 0..32767
  int col = i >> 5, j = i & 31;
  w1t[col * 32 + j] = W1[j * 1024 + col];
}

// ---- per-node: P2 = h@W2 + b2
__global__ void k_p2(const float* __restrict__ h, const float* __restrict__ W2,
                     const float* __restrict__ b2, float* __restrict__ P2) {
  __shared__ float w2s[1024];
  int t = threadIdx.x;
  for (int i = t; i < 1024; i += 256) w2s[i] = W2[i];
  __syncthreads();
  int nl = t >> 5, m = t & 31;
  int n = blockIdx.x * 8 + nl;
  const float* hrow = h + n * 32;
  float a = b2[m];
  #pragma unroll
  for (int j = 0; j < 32; ++j) a = fmaf(hrow[j], w2s[j * 32 + m], a);
  P2[n * 32 + m] = a;
}

// ---- edge kernel: 1 thread = 1 edge, exact fp32 everywhere
__global__ __launch_bounds__(256) void k_edge(
    const float* __restrict__ h, const int* __restrict__ feat,
    const int* __restrict__ src_idx, const int* __restrict__ dst_idx,
    const float* __restrict__ emb_src, const float* __restrict__ emb_dst,
    const float* __restrict__ W_edge, const float* __restrict__ b_edge,
    const float* __restrict__ b1, const float* __restrict__ W3,
    const float* __restrict__ b3, const float* __restrict__ w1t,
    const float* __restrict__ P2, float* __restrict__ out,
    float* __restrict__ bn_acc) {
  __shared__ float red[4][64];
  const int t = threadIdx.x;
  const int e = blockIdx.x * 256 + t;
  const int si = src_idx[e], di = dst_idx[e];
  const int fs = feat[si], fd = feat[di];

  // P2[dst] row in registers (static indexing only)
  float p2r[32];
  #pragma unroll
  for (int d = 0; d < 32; ++d) p2r[d] = P2[di * 32 + d];

  float vout[32];
  #pragma unroll
  for (int m = 0; m < 32; ++m) vout[m] = b_edge[m] + b3[m];

  // local term: [emb_src[feat[src]], emb_dst[feat[dst]]] @ W_edge
  #pragma unroll
  for (int j = 0; j < 32; ++j) {
    float ej = emb_src[fs * 32 + j];
    #pragma unroll
    for (int m = 0; m < 32; ++m) vout[m] = fmaf(ej, W_edge[j * 32 + m], vout[m]);
  }
  #pragma unroll
  for (int j = 0; j < 32; ++j) {
    float ej = emb_dst[fd * 32 + j];
    #pragma unroll
    for (int m = 0; m < 32; ++m) vout[m] = fmaf(ej, W_edge[(32 + j) * 32 + m], vout[m]);
  }

  // h[src] row in registers (static indexing only)
  float hs[32];
  #pragma unroll
  for (int j = 0; j < 32; ++j) hs[j] = h[si * 32 + j];

  // global term: G[k] = sum_d (sum_j hs[j]*W1[j][k*32+d] + b1[k*32+d]) * P2[dst][d]
  //              vout[m] += sum_k G[k]*W3[k][m]
  for (int k = 0; k < 32; ++k) {
    float gk = 0.f;
    #pragma unroll
    for (int d = 0; d < 32; ++d) {
      const float* w1c = w1t + (k * 32 + d) * 32;   // j-contiguous, wave-uniform
      float tmp = b1[k * 32 + d];
      #pragma unroll
      for (int j = 0; j < 32; ++j) tmp = fmaf(hs[j], w1c[j], tmp);
      gk = fmaf(tmp, p2r[d], gk);
    }
    #pragma unroll
    for (int m = 0; m < 32; ++m) vout[m] = fmaf(gk, W3[k * 32 + m], vout[m]);
  }

  // write pre-BN output
  #pragma unroll
  for (int m = 0; m < 32; ++m) out[e * 32 + m] = vout[m];

  // BN partials: per-channel butterfly over the wave, cross-wave via LDS, 1 atomic set per block
  const int lane = t & 63, wv = t >> 6;
  #pragma unroll
  for (int m = 0; m < 32; ++m) {
    float a = vout[m];
    float b = vout[m] * vout[m];
    #pragma unroll
    for (int off = 1; off < 64; off <<= 1) {
      a += __shfl_xor(a, off);
      b += __shfl_xor(b, off);
    }
    if (lane == 0) { red[wv][m] = a; red[wv][32 + m] = b; }
  }
  __syncthreads();
  if (t < 64) {
    float acc = red[0][t] + red[1][t] + red[2][t] + red[3][t];
    atomicAdd(&bn_acc[t], acc);   // [0..31]=sum, [32..63]=sumsq
  }
}

// ---- BN finalize: scale/shift per channel
__global__ void k_bnfin(const float* __restrict__ bn, const float* __restrict__ gamma,
                        const float* __restrict__ beta, float* __restrict__ osc) {
  int m = threadIdx.x;
  float mean = bn[m] / (float)N_EDGES;
  float var = fmaxf(bn[32 + m] / (float)N_EDGES - mean * mean, 0.f);
  float sc = gamma[m] * rsqrtf(var + EPSBN);
  osc[m] = sc;
  osc[32 + m] = beta[m] - mean * sc;
}

// ---- normalize + ReLU, in-place on d_out
__global__ void k_norm(float* __restrict__ out, const float* __restrict__ sc) {
  __shared__ float s[64];
  if (threadIdx.x < 64) s[threadIdx.x] = sc[threadIdx.x];
  __syncthreads();
  const int total = N_EDGES * 32 / 4;
  for (int i = blockIdx.x * blockDim.x + threadIdx.x; i < total; i += gridDim.x * blockDim.x) {
    floatx4 v = ((floatx4*)out)[i];
    int mb = (i * 4) & 31;
    floatx4 r;
    #pragma unroll
    for (int cc = 0; cc < 4; ++cc)
      r[cc] = fmaxf(fmaf(v[cc], s[mb + cc], s[32 + mb + cc]), 0.f);
    ((floatx4*)out)[i] = r;
  }
}

extern "C" void kernel_launch(void* const* d_in, const int* in_sizes, int n_in,
                              void* d_out, int out_size, void* d_ws, size_t ws_size,
                              hipStream_t stream) {
  const float* h       = (const float*)d_in[0];
  const int*   feat    = (const int*)d_in[2];
  const int*   srci    = (const int*)d_in[3];
  const int*   dsti    = (const int*)d_in[4];
  const float* emb_src = (const float*)d_in[5];
  const float* emb_dst = (const float*)d_in[6];
  const float* W_edge  = (const float*)d_in[7];
  const float* b_edge  = (const float*)d_in[8];
  const float* W1      = (const float*)d_in[9];
  const float* b1      = (const float*)d_in[10];
  const float* W2      = (const float*)d_in[11];
  const float* b2      = (const float*)d_in[12];
  const float* W3      = (const float*)d_in[13];
  const float* b3      = (const float*)d_in[14];
  const float* gamma   = (const float*)d_in[15];
  const float* beta    = (const float*)d_in[16];
  float* out = (float*)d_out;
  char* ws = (char*)d_ws;

  // ws layout
  float* bn   = (float*)(ws + 0);        // sum[32], sumsq[32]
  float* osc  = (float*)(ws + 256);      // scale[32], shift[32]
  float* w1t  = (float*)(ws + 512);      // 128KB: W1 transposed f32
  float* P2   = (float*)(ws + 512 + 131072);   // 5.12MB
  if (ws_size < (size_t)(512 + 131072 + 5120000)) return;

  hipMemsetAsync(bn, 0, 256, stream);
  k_setup<<<128, 256, 0, stream>>>(W1, w1t);
  k_p2<<<N_NODES / 8, 256, 0, stream>>>(h, W2, b2, P2);
  k_edge<<<N_EDGES / 256, 256, 0, stream>>>(h, feat, srci, dsti, emb_src, emb_dst,
                                            W_edge, b_edge, b1, W3, b3, w1t, P2, out, bn);
  k_bnfin<<<1, 32, 0, stream>>>(bn, gamma, beta, osc);
  k_norm<<<2048, 256, 0, stream>>>(out, osc);
}

// Round 6
// 841.895 us; speedup vs baseline: 1.0427x; 1.0427x over previous
//
#include <hip/hip_runtime.h>

#define N_NODES 40000
#define N_EDGES 320000
#define EPSBN 1e-5f

typedef float floatx4 __attribute__((ext_vector_type(4)));
typedef _Float16 f16x8 __attribute__((ext_vector_type(8)));

__device__ inline floatx4 mfma16(f16x8 a, f16x8 b, floatx4 c) {
  return __builtin_amdgcn_mfma_f32_16x16x32_f16(a, b, c, 0, 0, 0);
}

__device__ inline f16x8 cvt8(floatx4 a, floatx4 b) {
  f16x8 r;
  r[0]=(_Float16)a[0]; r[1]=(_Float16)a[1]; r[2]=(_Float16)a[2]; r[3]=(_Float16)a[3];
  r[4]=(_Float16)b[0]; r[5]=(_Float16)b[1]; r[6]=(_Float16)b[2]; r[7]=(_Float16)b[3];
  return r;
}

// ---- precompute: w1t fp16 (unswizzled col-major), Tsrc/Tdst tables, w3h fp16, BB
__global__ void k_pre(const float* __restrict__ W1, const float* __restrict__ b1,
                      const float* __restrict__ W3, const float* __restrict__ W_edge,
                      const float* __restrict__ b_edge, const float* __restrict__ b3,
                      const float* __restrict__ emb_src, const float* __restrict__ emb_dst,
                      unsigned short* __restrict__ w1t, float* __restrict__ Tsrc,
                      float* __restrict__ Tdst, unsigned short* __restrict__ w3h,
                      float* __restrict__ BB) {
  int t = threadIdx.x, bid = blockIdx.x;
  if (bid < 128) {                       // w1t[q*32 + j] = fp16(W1[j][q]), q = col of W1
    int i = bid * 256 + t;               // 0..32767
    int q = i >> 5, j = i & 31;
    w1t[i] = (unsigned short)__builtin_bit_cast(unsigned short, (_Float16)W1[j * 1024 + q]);
  } else if (bid < 144) {                // Tsrc[v][m] = sum_j emb_src[v][j]*W_edge[j][m] + b_edge[m] + b3[m]
    int i = (bid - 128) * 256 + t;       // 0..4095
    int v = i >> 5, m = i & 31;
    float a = b_edge[m] + b3[m];
    #pragma unroll
    for (int j = 0; j < 32; ++j) a = fmaf(emb_src[v * 32 + j], W_edge[j * 32 + m], a);
    Tsrc[i] = a;
  } else if (bid < 160) {                // Tdst[v][m] = sum_j emb_dst[v][j]*W_edge[32+j][m]
    int i = (bid - 144) * 256 + t;
    int v = i >> 5, m = i & 31;
    float a = 0.f;
    #pragma unroll
    for (int j = 0; j < 32; ++j) a = fmaf(emb_dst[v * 32 + j], W_edge[(32 + j) * 32 + m], a);
    Tdst[i] = a;
  } else if (bid == 160) {               // w3h = fp16(W3)
    #pragma unroll
    for (int i = 0; i < 4; ++i) {
      int idx = t * 4 + i;
      w3h[idx] = (unsigned short)__builtin_bit_cast(unsigned short, (_Float16)W3[idx]);
    }
  } else {                               // BB[d][m] = sum_k b1[k*32+d]*W3[k][m]
    int i = (bid - 161) * 256 + t;       // 0..1023
    int d = i >> 5, m = i & 31;
    float a = 0.f;
    #pragma unroll
    for (int k = 0; k < 32; ++k) a = fmaf(b1[k * 32 + d], W3[k * 32 + m], a);
    BB[i] = a;
  }
}

// ---- per-node: P2 = h@W2+b2 ; P2c = P2 @ BB   (verified in rounds 0-5)
__global__ void k_p2(const float* __restrict__ h, const float* __restrict__ W2,
                     const float* __restrict__ b2, const float* __restrict__ BB,
                     float* __restrict__ P2, float* __restrict__ P2c) {
  __shared__ float w2s[1024], bbs[1024], p2l[8][32];
  int t = threadIdx.x;
  for (int i = t; i < 1024; i += 256) { w2s[i] = W2[i]; bbs[i] = BB[i]; }
  __syncthreads();
  int nl = t >> 5, m = t & 31;
  int n = blockIdx.x * 8 + nl;
  const float* hrow = h + n * 32;
  float a = b2[m];
  #pragma unroll
  for (int j = 0; j < 32; ++j) a = fmaf(hrow[j], w2s[j * 32 + m], a);
  P2[n * 32 + m] = a;
  p2l[nl][m] = a;
  __syncthreads();
  float cacc = 0.f;
  #pragma unroll
  for (int d = 0; d < 32; ++d) cacc = fmaf(p2l[nl][d], bbs[d * 32 + m], cacc);
  P2c[n * 32 + m] = cacc;
}

// ---- main edge kernel: 8 waves/block, 16 edges/wave, MFMA only for W1 x h
__global__ __launch_bounds__(512, 4) void k_edge(
    const float* __restrict__ h, const int* __restrict__ feat,
    const int* __restrict__ src_idx, const int* __restrict__ dst_idx,
    const unsigned short* __restrict__ w1t, const unsigned short* __restrict__ w3h,
    const float* __restrict__ Tsrc, const float* __restrict__ Tdst,
    const float* __restrict__ P2, const float* __restrict__ P2c,
    float* __restrict__ out, float* __restrict__ bn_acc) {
  __shared__ unsigned short w1l[32768];   // 64KB fp16 W1 (col-major: [q][j])
  __shared__ unsigned short w3l[1024];    // 2KB fp16 W3 [k][m]
  __shared__ float red[8][64];
  const int t = threadIdx.x;
  for (int i = t; i < 4096; i += 512)
    ((floatx4*)w1l)[i] = ((const floatx4*)w1t)[i];
  if (t < 128) ((floatx4*)w3l)[t] = ((const floatx4*)w3h)[t];

  const int lane = t & 63;
  const int wv = t >> 6;
  const int c = lane & 15;    // edge selector within wave's 16-edge group
  const int g4 = lane >> 4;   // j-slot / d-slot / channel-slice selector

  float s8[8] = {0,0,0,0,0,0,0,0}, q8[8] = {0,0,0,0,0,0,0,0};

  __syncthreads();

  // A-fragment source: element (k*32 + c)*32 + g4*8  (row d=c of W1-col-block k), +512 for d=16+c
  const unsigned short* awp = w1l + c * 32 + g4 * 8;
  const unsigned short* w3p = w3l + g4 * 8;

  for (int grp = blockIdx.x; grp < N_EDGES / 128; grp += gridDim.x) {
    const int e = grp * 128 + wv * 16 + c;
    const int si = src_idx[e];
    const int di = dst_idx[e];
    const int fs = feat[si];
    const int fd = feat[di];

    const floatx4* hp = (const floatx4*)(h + si * 32 + g4 * 8);
    f16x8 bh = cvt8(hp[0], hp[1]);           // B[j][e=c] = h[src_c][j], j-slots g4*8..+7
    const floatx4* pp = (const floatx4*)(P2 + di * 32);
    floatx4 p2a = pp[g4];                    // P2[dst_c][g4*4 .. +3]
    floatx4 p2b = pp[g4 + 4];                // P2[dst_c][16+g4*4 .. +3]

    float v8[8] = {0,0,0,0,0,0,0,0};
    #pragma unroll
    for (int k = 0; k < 32; ++k) {
      f16x8 aw0 = *(const f16x8*)(awp + k * 1024);        // A[d=c][j] = W1[j][k*32+c]
      f16x8 aw1 = *(const f16x8*)(awp + k * 1024 + 512);  // d = 16+c block
      floatx4 z = {0.f, 0.f, 0.f, 0.f};
      floatx4 m0 = mfma16(aw0, bh, z);       // C'[d=g4*4+r][e=c]
      floatx4 m1 = mfma16(aw1, bh, z);       // C'[16+g4*4+r][e=c]
      float ps = m0[0] * p2a[0];
      ps = fmaf(m0[1], p2a[1], ps);
      ps = fmaf(m0[2], p2a[2], ps);
      ps = fmaf(m0[3], p2a[3], ps);
      ps = fmaf(m1[0], p2b[0], ps);
      ps = fmaf(m1[1], p2b[1], ps);
      ps = fmaf(m1[2], p2b[2], ps);
      ps = fmaf(m1[3], p2b[3], ps);
      ps += __shfl_xor(ps, 16);
      ps += __shfl_xor(ps, 32);              // all lanes: G[e=c][k]
      const f16x8 w3k = *(const f16x8*)(w3p + k * 32);   // W3[k][g4*8 .. +7]
      #pragma unroll
      for (int i = 0; i < 8; ++i) v8[i] = fmaf(ps, (float)w3k[i], v8[i]);
    }

    // epilogue: table gathers + write channels g4*8..+7 of edge e
    const floatx4* tsp = (const floatx4*)(Tsrc + fs * 32 + g4 * 8);
    const floatx4* tdp = (const floatx4*)(Tdst + fd * 32 + g4 * 8);
    const floatx4* pcp = (const floatx4*)(P2c + di * 32 + g4 * 8);
    floatx4 o0, o1;
    #pragma unroll
    for (int i = 0; i < 4; ++i) {
      o0[i] = v8[i] + tsp[0][i] + tdp[0][i] + pcp[0][i];
      o1[i] = v8[4 + i] + tsp[1][i] + tdp[1][i] + pcp[1][i];
    }
    *(floatx4*)(out + e * 32 + g4 * 8) = o0;
    *(floatx4*)(out + e * 32 + g4 * 8 + 4) = o1;
    #pragma unroll
    for (int i = 0; i < 4; ++i) {
      s8[i] += o0[i];     q8[i] = fmaf(o0[i], o0[i], q8[i]);
      s8[4 + i] += o1[i]; q8[4 + i] = fmaf(o1[i], o1[i], q8[4 + i]);
    }
  }

  // BN partials: reduce over c (xor 1,2,4,8), then cross-wave LDS, then atomics
  #pragma unroll
  for (int i = 0; i < 8; ++i) {
    float a = s8[i], b = q8[i];
    #pragma unroll
    for (int off = 1; off < 16; off <<= 1) {
      a += __shfl_xor(a, off);
      b += __shfl_xor(b, off);
    }
    if (c == 0) { red[wv][g4 * 8 + i] = a; red[wv][32 + g4 * 8 + i] = b; }
  }
  __syncthreads();
  if (t < 64) {
    float acc = 0.f;
    #pragma unroll
    for (int w = 0; w < 8; ++w) acc += red[w][t];
    atomicAdd(&bn_acc[t], acc);   // [0..31]=sum, [32..63]=sumsq
  }
}

// ---- BN finalize
__global__ void k_bnfin(const float* __restrict__ bn, const float* __restrict__ gamma,
                        const float* __restrict__ beta, float* __restrict__ osc) {
  int m = threadIdx.x;
  float mean = bn[m] / (float)N_EDGES;
  float var = fmaxf(bn[32 + m] / (float)N_EDGES - mean * mean, 0.f);
  float sc = gamma[m] * rsqrtf(var + EPSBN);
  osc[m] = sc;
  osc[32 + m] = beta[m] - mean * sc;
}

// ---- normalize + ReLU
__global__ void k_norm(float* __restrict__ out, const float* __restrict__ sc) {
  __shared__ float s[64];
  if (threadIdx.x < 64) s[threadIdx.x] = sc[threadIdx.x];
  __syncthreads();
  const int total = N_EDGES * 32 / 4;
  for (int i = blockIdx.x * blockDim.x + threadIdx.x; i < total; i += gridDim.x * blockDim.x) {
    floatx4 v = ((floatx4*)out)[i];
    int mb = (i * 4) & 31;
    floatx4 r;
    #pragma unroll
    for (int cc = 0; cc < 4; ++cc)
      r[cc] = fmaxf(fmaf(v[cc], s[mb + cc], s[32 + mb + cc]), 0.f);
    ((floatx4*)out)[i] = r;
  }
}

extern "C" void kernel_launch(void* const* d_in, const int* in_sizes, int n_in,
                              void* d_out, int out_size, void* d_ws, size_t ws_size,
                              hipStream_t stream) {
  const float* h       = (const float*)d_in[0];
  const int*   feat    = (const int*)d_in[2];
  const int*   srci    = (const int*)d_in[3];
  const int*   dsti    = (const int*)d_in[4];
  const float* emb_src = (const float*)d_in[5];
  const float* emb_dst = (const float*)d_in[6];
  const float* W_edge  = (const float*)d_in[7];
  const float* b_edge  = (const float*)d_in[8];
  const float* W1      = (const float*)d_in[9];
  const float* b1      = (const float*)d_in[10];
  const float* W2      = (const float*)d_in[11];
  const float* b2      = (const float*)d_in[12];
  const float* W3      = (const float*)d_in[13];
  const float* b3      = (const float*)d_in[14];
  const float* gamma   = (const float*)d_in[15];
  const float* beta    = (const float*)d_in[16];
  float* out = (float*)d_out;
  char* ws = (char*)d_ws;

  // ws layout
  float* bn            = (float*)(ws + 0);       // 256B
  float* osc           = (float*)(ws + 256);     // 256B
  float* Tsrc          = (float*)(ws + 512);     // 16KB
  float* Tdst          = (float*)(ws + 512 + 16384);
  float* BB            = (float*)(ws + 512 + 32768);            // 4KB
  unsigned short* w3h  = (unsigned short*)(ws + 512 + 36864);   // 2KB
  unsigned short* w1t  = (unsigned short*)(ws + 40960);         // 64KB
  float* P2            = (float*)(ws + 106496);                 // 5.12MB
  float* P2c           = (float*)(ws + 106496 + 5120000);       // 5.12MB
  if (ws_size < (size_t)(106496 + 2 * 5120000)) return;

  hipMemsetAsync(bn, 0, 256, stream);
  k_pre<<<165, 256, 0, stream>>>(W1, b1, W3, W_edge, b_edge, b3, emb_src, emb_dst,
                                 w1t, Tsrc, Tdst, w3h, BB);
  k_p2<<<N_NODES / 8, 256, 0, stream>>>(h, W2, b2, BB, P2, P2c);
  k_edge<<<512, 512, 0, stream>>>(h, feat, srci, dsti, w1t, w3h, Tsrc, Tdst,
                                  P2, P2c, out, bn);
  k_bnfin<<<1, 32, 0, stream>>>(bn, gamma, beta, osc);
  k_norm<<<2048, 256, 0, stream>>>(out, osc);
}